// Round 7
// baseline (490.838 us; speedup 1.0000x reference)
//
#include <hip/hip_runtime.h>
#include <hip/hip_bf16.h>

#define DIVUP(a, b) (((a) + (b) - 1) / (b))

typedef __attribute__((ext_vector_type(8))) short bf16x8;
typedef __attribute__((ext_vector_type(4))) float f32x4;

// ---------- helpers ----------
__device__ __forceinline__ float bf2f(unsigned short u) {
    union { unsigned int i; float f; } v;
    v.i = ((unsigned int)u) << 16;
    return v.f;
}
__device__ __forceinline__ unsigned short f2bfu(float x) {
    return __hip_bfloat16_raw(__float2bfloat16(x)).x;   // RNE
}
__device__ __forceinline__ float gload(const void* p, int i, int isbf) {
    return isbf ? bf2f(((const unsigned short*)p)[i]) : ((const float*)p)[i];
}

// ================= CSR build: counting sort, zero global atomics =================
// Round-13 lesson (reverted experiment): direct global-atomic scatter cost 300us —
// random 4B stores are ~64B HBM RMW each plus a serialized atomic-return chain.
// The two-level sort's extra sequential traffic is all COALESCED (~6x cheaper/B).
#define CHUNK 2048

__global__ void __launch_bounds__(256) parta_hist(const int* __restrict__ col,
                                                  int* __restrict__ cntRB,
                                                  int E, int B, int NB) {
    __shared__ int h[512];
    for (int i = threadIdx.x; i < NB; i += 256) h[i] = 0;
    __syncthreads();
    const int base = blockIdx.x * CHUNK;
#pragma unroll
    for (int k = 0; k < CHUNK / 256; ++k) {
        const int e = base + k * 256 + threadIdx.x;
        if (e < E) atomicAdd(&h[col[e] >> 8], 1);
    }
    __syncthreads();
    for (int i = threadIdx.x; i < NB; i += 256) cntRB[i * B + blockIdx.x] = h[i];
}

__global__ void __launch_bounds__(256) scan_block_sums(const int* __restrict__ cnt,
                                                       int* __restrict__ bsum, int n) {
    __shared__ int red[256];
    const int base = blockIdx.x * 1024;
    int s = 0;
    for (int i = threadIdx.x; i < 1024; i += 256) {
        const int idx = base + i;
        s += (idx < n) ? cnt[idx] : 0;
    }
    red[threadIdx.x] = s;
    __syncthreads();
    for (int off = 128; off > 0; off >>= 1) {
        if (threadIdx.x < off) red[threadIdx.x] += red[threadIdx.x + off];
        __syncthreads();
    }
    if (threadIdx.x == 0) bsum[blockIdx.x] = red[0];
}

// single-block exclusive scan with carry loop + folded dtype detection
__global__ void __launch_bounds__(256) scan_bsum(int* __restrict__ bsum, int nb,
                                                 const void* __restrict__ feat,
                                                 int* __restrict__ flag) {
    __shared__ int tmp[256];
    __shared__ int carry;
    __shared__ int dcnt;
    const int x = threadIdx.x;
    if (x == 0) { carry = 0; dcnt = 0; }
    __syncthreads();
    {   // dtype detect: plausible-bf16 heuristic over first 2048 halfwords
        const unsigned short* u = (const unsigned short*)feat;
        int c = 0;
#pragma unroll
        for (int rep = 0; rep < 4; ++rep) {
            const float v = fabsf(bf2f(u[x * 2 + rep * 512]));
            c += (v > 1e-4f && v < 10.0f) ? 1 : 0;
        }
        atomicAdd(&dcnt, c);
        __syncthreads();
        if (x == 0) *flag = (dcnt > 512) ? 1 : 0;
    }
    for (int base = 0; base < nb; base += 256) {
        const int idx = base + x;
        const int v = (idx < nb) ? bsum[idx] : 0;
        tmp[x] = v;
        __syncthreads();
        int val = v;
        for (int off = 1; off < 256; off <<= 1) {
            const int t = (x >= off) ? tmp[x - off] : 0;
            __syncthreads();
            val += t;
            tmp[x] = val;
            __syncthreads();
        }
        if (idx < nb) bsum[idx] = carry + val - v;   // exclusive
        __syncthreads();                              // all read carry first
        if (x == 255) carry += val;                   // chunk total
        __syncthreads();
    }
}

__global__ void __launch_bounds__(256) scan_final(const int* __restrict__ cnt,
                                                  const int* __restrict__ bsum,
                                                  int* __restrict__ outp, int n) {
    __shared__ int tsum[256];
    const int base = blockIdx.x * 1024;
    const int x = threadIdx.x;
    int v[4];
    int s = 0;
#pragma unroll
    for (int k = 0; k < 4; ++k) {
        const int idx = base + x * 4 + k;
        v[k] = (idx < n) ? cnt[idx] : 0;
        s += v[k];
    }
    tsum[x] = s;
    __syncthreads();
    int val = s;
    for (int off = 1; off < 256; off <<= 1) {
        const int t = (x >= off) ? tsum[x - off] : 0;
        __syncthreads();
        val += t;
        tsum[x] = val;
        __syncthreads();
    }
    int prefix = bsum[blockIdx.x] + (val - s);
#pragma unroll
    for (int k = 0; k < 4; ++k) {
        const int idx = base + x * 4 + k;
        if (idx < n) outp[idx] = prefix;
        prefix += v[k];
    }
}

__global__ void __launch_bounds__(256) parta_scatter(const int* __restrict__ row,
                                                     const int* __restrict__ col,
                                                     const int* __restrict__ seg_off,
                                                     int* __restrict__ part,
                                                     int E, int B, int NB) {
    __shared__ int cur[512];
    for (int i = threadIdx.x; i < NB; i += 256) cur[i] = seg_off[i * B + blockIdx.x];
    __syncthreads();
    const int base = blockIdx.x * CHUNK;
    int c[CHUNK / 256], r[CHUNK / 256];
#pragma unroll
    for (int k = 0; k < CHUNK / 256; ++k) {
        const int e = base + k * 256 + threadIdx.x;
        if (e < E) { c[k] = col[e]; r[k] = row[e]; }
    }
#pragma unroll
    for (int k = 0; k < CHUNK / 256; ++k) {
        const int e = base + k * 256 + threadIdx.x;
        if (e < E) {
            const int p = atomicAdd(&cur[c[k] >> 8], 1);
            part[p] = (c[k] & 255) | (r[k] << 8);   // 4B packed: low8=col-in-bucket
        }
    }
}

// 1024 threads: NB=391 blocks is only 1.5/CU; 16 waves/block restores latency
// hiding for the two segment passes.
__global__ void __launch_bounds__(1024) csr_build(const int* __restrict__ part,
                                                  const int* __restrict__ seg_off,
                                                  int* __restrict__ rowptr,
                                                  int* __restrict__ cnt,
                                                  float* __restrict__ dinv,
                                                  int* __restrict__ csr,
                                                  int E, int B, int NB, int N) {
    __shared__ int cl[256];
    __shared__ int sc[256];
    const int r  = blockIdx.x;
    const int c0 = r << 8;
    const int s0 = seg_off[(size_t)r * B];
    const int s1 = (r == NB - 1) ? E : seg_off[(size_t)(r + 1) * B];
    const int x  = threadIdx.x;
    if (x < 256) cl[x] = 0;
    __syncthreads();
    for (int i = s0 + x; i < s1; i += 1024)
        atomicAdd(&cl[part[i] & 255], 1);
    __syncthreads();
    int v = 0, val = 0;
    if (x < 256) { v = cl[x]; sc[x] = v; val = v; }
    __syncthreads();
    for (int off = 1; off < 256; off <<= 1) {
        const int t = (x >= off && x < 256) ? sc[x - off] : 0;
        __syncthreads();
        if (x < 256) { val += t; sc[x] = val; }
        __syncthreads();
    }
    const int excl = val - v;
    if (x < 256) {
        const int c = c0 + x;
        if (c < N) {
            rowptr[c] = s0 + excl;
            cnt[c]    = v;
            dinv[c]   = rsqrtf((float)v + 1.0f);
        }
        cl[x] = s0 + excl;   // reuse as cursor
    }
    __syncthreads();
    for (int i = s0 + x; i < s1; i += 1024) {
        const int pr = part[i];
        const int p = atomicAdd(&cl[pr & 255], 1);
        csr[p] = (pr >> 8) << 7;   // row*128: byte offset template, shifted per layer
    }
}

// ================= MFMA GEMM: y = bf16((x @ W) * dinv[node]) =================
// Block = 4 waves x 16 nodes. Verified layouts (cdna docs m89/m91/m120).
// Only layer 1 uses this now; layers 2/3 GEMMs are fused into the aggregates.
template<int F_IN, int F_OUT, int XMODE>
__global__ void __launch_bounds__(256) gemm_mfma(const void* __restrict__ x,
                                                 const void* __restrict__ W,
                                                 const float* __restrict__ dinv,
                                                 unsigned short* __restrict__ y,
                                                 int n, const int* __restrict__ flag) {
    constexpr int KS = F_IN / 32;        // k-slices
    constexpr int NT = F_OUT / 16;       // f-tiles
    constexpr int WPAD = F_IN + 8;       // +16B row pad vs bank conflicts
    const int isbf = *flag;
    __shared__ unsigned short Wt[F_OUT * WPAD];

    for (int i = threadIdx.x; i < F_IN * F_OUT; i += 256) {
        const int k = i / F_OUT, nn = i % F_OUT;
        Wt[nn * WPAD + k] = f2bfu(gload(W, i, isbf));
    }
    __syncthreads();

    const int lane = threadIdx.x & 63;
    const int wid  = threadIdx.x >> 6;
    const int m    = lane & 15;
    const int quad = lane >> 4;
    const int nodeA = blockIdx.x * 64 + wid * 16 + m;

    bf16x8 afr[KS];
    if (nodeA < n) {
        if (XMODE == 1 || isbf) {
            const unsigned short* xr = (const unsigned short*)x + (size_t)nodeA * F_IN;
#pragma unroll
            for (int s = 0; s < KS; ++s)
                afr[s] = *(const bf16x8*)(xr + s * 32 + quad * 8);
        } else {
            const float* xr = (const float*)x + (size_t)nodeA * F_IN;
#pragma unroll
            for (int s = 0; s < KS; ++s) {
                const float4 v0 = *(const float4*)(xr + s * 32 + quad * 8);
                const float4 v1 = *(const float4*)(xr + s * 32 + quad * 8 + 4);
                bf16x8 a;
                a[0] = (short)f2bfu(v0.x); a[1] = (short)f2bfu(v0.y);
                a[2] = (short)f2bfu(v0.z); a[3] = (short)f2bfu(v0.w);
                a[4] = (short)f2bfu(v1.x); a[5] = (short)f2bfu(v1.y);
                a[6] = (short)f2bfu(v1.z); a[7] = (short)f2bfu(v1.w);
                afr[s] = a;
            }
        }
    } else {
#pragma unroll
        for (int s = 0; s < KS; ++s) afr[s] = (bf16x8)(short)0;
    }

    f32x4 acc[NT];
#pragma unroll
    for (int t = 0; t < NT; ++t) acc[t] = (f32x4)0.f;

#pragma unroll
    for (int t = 0; t < NT; ++t) {
#pragma unroll
        for (int s = 0; s < KS; ++s) {
            const bf16x8 bfr = *(const bf16x8*)(Wt + (t * 16 + m) * WPAD + s * 32 + quad * 8);
            acc[t] = __builtin_amdgcn_mfma_f32_16x16x32_bf16(afr[s], bfr, acc[t], 0, 0, 0);
        }
    }

#pragma unroll
    for (int r = 0; r < 4; ++r) {
        const int ng = blockIdx.x * 64 + wid * 16 + quad * 4 + r;
        if (ng < n) {
            const float scl = dinv[ng];
#pragma unroll
            for (int t = 0; t < NT; ++t) {
                const int f = t * 16 + m;
                y[(size_t)ng * F_OUT + f] = f2bfu(acc[t][r] * scl);
            }
        }
    }
}

// ---------- aggregate core: node-group = 4 edge-slots x L4 lanes, ushort4 ----------
template<int F, int SH>
__device__ __forceinline__ void agg_core(const unsigned short* __restrict__ y,
                                         const int* __restrict__ csr,
                                         int beg, int deg, int e, int ub,
                                         float4& a) {
    const char* yb = (const char*)y;
    int j = 0;
    for (; j + 32 <= deg; j += 32) {
        int o[8];
#pragma unroll
        for (int k = 0; k < 8; ++k) o[k] = csr[beg + j + e + 4 * k] >> SH;
        float4 v[8];
#pragma unroll
        for (int k = 0; k < 8; ++k) {
            const ushort4 t = *(const ushort4*)(yb + o[k] + ub);
            v[k] = make_float4(bf2f(t.x), bf2f(t.y), bf2f(t.z), bf2f(t.w));
        }
#pragma unroll
        for (int s = 1; s < 8; s <<= 1)
#pragma unroll
            for (int k = 0; k < 8; k += 2 * s) {
                v[k].x += v[k + s].x; v[k].y += v[k + s].y;
                v[k].z += v[k + s].z; v[k].w += v[k + s].w;
            }
        a.x += v[0].x; a.y += v[0].y; a.z += v[0].z; a.w += v[0].w;
    }
    if (j + 16 <= deg) {
        int o[4];
#pragma unroll
        for (int k = 0; k < 4; ++k) o[k] = csr[beg + j + e + 4 * k] >> SH;
        float4 v[4];
#pragma unroll
        for (int k = 0; k < 4; ++k) {
            const ushort4 t = *(const ushort4*)(yb + o[k] + ub);
            v[k] = make_float4(bf2f(t.x), bf2f(t.y), bf2f(t.z), bf2f(t.w));
        }
#pragma unroll
        for (int s = 1; s < 4; s <<= 1)
#pragma unroll
            for (int k = 0; k < 4; k += 2 * s) {
                v[k].x += v[k + s].x; v[k].y += v[k + s].y;
                v[k].z += v[k + s].z; v[k].w += v[k + s].w;
            }
        a.x += v[0].x; a.y += v[0].y; a.z += v[0].z; a.w += v[0].w;
        j += 16;
    }
    if (j + 8 <= deg) {
        int o0 = csr[beg + j + e] >> SH;
        int o1 = csr[beg + j + e + 4] >> SH;
        const ushort4 t0 = *(const ushort4*)(yb + o0 + ub);
        const ushort4 t1 = *(const ushort4*)(yb + o1 + ub);
        a.x += bf2f(t0.x) + bf2f(t1.x); a.y += bf2f(t0.y) + bf2f(t1.y);
        a.z += bf2f(t0.z) + bf2f(t1.z); a.w += bf2f(t0.w) + bf2f(t1.w);
        j += 8;
    }
    for (; j < deg; j += 4) {
        if (j + e < deg) {
            const int o = csr[beg + j + e] >> SH;
            const ushort4 t = *(const ushort4*)(yb + o + ub);
            a.x += bf2f(t.x); a.y += bf2f(t.y); a.z += bf2f(t.z); a.w += bf2f(t.w);
        }
    }
}

// ---------- aggregate + epilogue + FUSED next-layer GEMM ----------
// Round-14: gemm2/gemm3 deleted as dispatches. After the slot-reduce every lane
// of the node-group holds its f-quad of the relu'd output row (replicated across
// e-slots), so the next layer's y = (f @ Wn) * dinv is an L4-step shfl+FMA dot
// per lane (agg3_head pattern). Wn staged in LDS; shfl/FMA land on pipes that
// are ~70% idle in this latency-bound gather kernel.
template<int F, int SH, int FOUT>
__global__ void __launch_bounds__(256) aggregate_gemm(const unsigned short* __restrict__ y,
                                                      const int* __restrict__ csr,
                                                      const int* __restrict__ rowptr,
                                                      const int* __restrict__ cnt,
                                                      const float* __restrict__ dinv,
                                                      const void* __restrict__ b,
                                                      const void* __restrict__ Wn,
                                                      unsigned short* __restrict__ outf,
                                                      unsigned short* __restrict__ outy,
                                                      int n, const int* __restrict__ flag) {
    const int isbf = *flag;
    constexpr int L4  = F / 4;        // lanes per row (ushort4 each)
    constexpr int GL  = 4 * L4;       // lanes per node-group (4 edge slots)
    constexpr int NPW = 64 / GL;      // nodes per wave
    constexpr int LGL = (GL == 64) ? 6 : (GL == 32) ? 5 : 4;

    __shared__ float Ws[F * FOUT];
    for (int i = threadIdx.x; i < F * FOUT; i += 256) Ws[i] = gload(Wn, i, isbf);
    __syncthreads();                  // before ANY return

    const int lane = threadIdx.x & 63;
    const int wv   = (blockIdx.x * 256 + threadIdx.x) >> 6;
    const int node = wv * NPW + (lane >> LGL);
    if (node >= n) return;
    const int g  = lane & (GL - 1);
    const int e  = g / L4;            // edge slot 0..3
    const int u  = g % L4;            // feature quad
    const int ub = u * 8;             // byte offset of this lane's ushort4

    float4 a = make_float4(0.f, 0.f, 0.f, 0.f);
    agg_core<F, SH>(y, csr, rowptr[node], cnt[node], e, ub, a);

    // reduce across the 4 edge-slots -> every lane holds quad u, replicated
#pragma unroll
    for (int mm = L4; mm < GL; mm <<= 1) {
        a.x += __shfl_xor(a.x, mm, 64); a.y += __shfl_xor(a.y, mm, 64);
        a.z += __shfl_xor(a.z, mm, 64); a.w += __shfl_xor(a.w, mm, 64);
    }

    // epilogue in ALL lanes (f32 r feeds the fused dot pre-rounding)
    const float d = dinv[node];
    float4 r;
    {
        const ushort4 t = *(const ushort4*)((const char*)y + (size_t)node * (F * 2) + ub);
        r.x = fmaxf(d * (a.x + bf2f(t.x)) + gload(b, 4 * u + 0, isbf), 0.f);
        r.y = fmaxf(d * (a.y + bf2f(t.y)) + gload(b, 4 * u + 1, isbf), 0.f);
        r.z = fmaxf(d * (a.z + bf2f(t.z)) + gload(b, 4 * u + 2, isbf), 0.f);
        r.w = fmaxf(d * (a.w + bf2f(t.w)) + gload(b, 4 * u + 3, isbf), 0.f);
    }
    if (g < L4) {
        ushort4 w;
        w.x = f2bfu(r.x); w.y = f2bfu(r.y); w.z = f2bfu(r.z); w.w = f2bfu(r.w);
        *(ushort4*)(outf + (size_t)node * F + 4 * u) = w;
    }

    // fused next-layer gemm: lane computes feature f = g & (FOUT-1)
    const int gbase = lane & ~(GL - 1);
    const int f = g & (FOUT - 1);
    float acc2 = 0.f;
#pragma unroll
    for (int q = 0; q < L4; ++q) {
        const int src = gbase + q;    // lane holding quad q of this node's row
        acc2 = fmaf(__shfl(r.x, src, 64), Ws[(4 * q + 0) * FOUT + f], acc2);
        acc2 = fmaf(__shfl(r.y, src, 64), Ws[(4 * q + 1) * FOUT + f], acc2);
        acc2 = fmaf(__shfl(r.z, src, 64), Ws[(4 * q + 2) * FOUT + f], acc2);
        acc2 = fmaf(__shfl(r.w, src, 64), Ws[(4 * q + 3) * FOUT + f], acc2);
    }
    if (g < FOUT) outy[(size_t)node * FOUT + f] = f2bfu(acc2 * d);
}

// ---------- layer-3 aggregate fused with dense head ----------
__global__ void __launch_bounds__(256) aggregate3_head(const unsigned short* __restrict__ y,
                                                       const int* __restrict__ csr,
                                                       const int* __restrict__ rowptr,
                                                       const int* __restrict__ cnt,
                                                       const float* __restrict__ dinv,
                                                       const void* __restrict__ b3,
                                                       const unsigned short* __restrict__ f1,
                                                       const unsigned short* __restrict__ f2,
                                                       const void* __restrict__ Wfc,
                                                       const void* __restrict__ bfc,
                                                       void* __restrict__ out,
                                                       int n, const int* __restrict__ flag) {
    const int isbf = *flag;
    __shared__ float Ws[112 * 16];
    for (int i = threadIdx.x; i < 112 * 16; i += 256) Ws[i] = gload(Wfc, i, isbf);
    __syncthreads();                              // before ANY return

    const int lane = threadIdx.x & 63;
    const int wv   = (blockIdx.x * 256 + threadIdx.x) >> 6;
    const int node = wv * 4 + (lane >> 4);        // F=16: GL=16, NPW=4
    if (node >= n) return;
    const int g  = lane & 15;
    const int e  = g >> 2;
    const int u  = g & 3;
    const int ub = u * 8;

    float4 a = make_float4(0.f, 0.f, 0.f, 0.f);
    agg_core<16, 2>(y, csr, rowptr[node], cnt[node], e, ub, a);

#pragma unroll
    for (int mm = 4; mm < 16; mm <<= 1) {
        a.x += __shfl_xor(a.x, mm, 64); a.y += __shfl_xor(a.y, mm, 64);
        a.z += __shfl_xor(a.z, mm, 64); a.w += __shfl_xor(a.w, mm, 64);
    }

    // epilogue in ALL lanes (every lane holds the quad for u = g&3)
    float4 r;
    {
        const ushort4 t = *(const ushort4*)((const char*)y + (size_t)node * 32 + ub);
        const float d = dinv[node];
        r.x = fmaxf(d * (a.x + bf2f(t.x)) + gload(b3, 4 * u + 0, isbf), 0.f);
        r.y = fmaxf(d * (a.y + bf2f(t.y)) + gload(b3, 4 * u + 1, isbf), 0.f);
        r.z = fmaxf(d * (a.z + bf2f(t.z)) + gload(b3, 4 * u + 2, isbf), 0.f);
        r.w = fmaxf(d * (a.w + bf2f(t.w)) + gload(b3, 4 * u + 3, isbf), 0.f);
    }

    // ---- head: lane computes output feature f = g for its group's node ----
    const int f = g;
    float acc = gload(bfc, f, isbf);
    const unsigned short* x1 = f1 + (size_t)node * 64;
#pragma unroll
    for (int k4 = 0; k4 < 16; ++k4) {
        const ushort4 xu = *(const ushort4*)(x1 + 4 * k4);
        acc = fmaf(bf2f(xu.x), Ws[(4 * k4 + 0) * 16 + f], acc);
        acc = fmaf(bf2f(xu.y), Ws[(4 * k4 + 1) * 16 + f], acc);
        acc = fmaf(bf2f(xu.z), Ws[(4 * k4 + 2) * 16 + f], acc);
        acc = fmaf(bf2f(xu.w), Ws[(4 * k4 + 3) * 16 + f], acc);
    }
    const unsigned short* x2 = f2 + (size_t)node * 32;
#pragma unroll
    for (int k4 = 0; k4 < 8; ++k4) {
        const ushort4 xu = *(const ushort4*)(x2 + 4 * k4);
        acc = fmaf(bf2f(xu.x), Ws[(64 + 4 * k4 + 0) * 16 + f], acc);
        acc = fmaf(bf2f(xu.y), Ws[(64 + 4 * k4 + 1) * 16 + f], acc);
        acc = fmaf(bf2f(xu.z), Ws[(64 + 4 * k4 + 2) * 16 + f], acc);
        acc = fmaf(bf2f(xu.w), Ws[(64 + 4 * k4 + 3) * 16 + f], acc);
    }
    // f3 via intra-group shuffles: src lane (lane&~15)+(k3>>2) holds comp k3&3
    const int gbase = lane & ~15;
#pragma unroll
    for (int k3 = 0; k3 < 16; k3 += 4) {
        const int src = gbase + (k3 >> 2);
        acc = fmaf(__shfl(r.x, src, 64), Ws[(96 + k3 + 0) * 16 + f], acc);
        acc = fmaf(__shfl(r.y, src, 64), Ws[(96 + k3 + 1) * 16 + f], acc);
        acc = fmaf(__shfl(r.z, src, 64), Ws[(96 + k3 + 2) * 16 + f], acc);
        acc = fmaf(__shfl(r.w, src, 64), Ws[(96 + k3 + 3) * 16 + f], acc);
    }
    acc = fmaxf(acc, 0.f);
    if (isbf) ((unsigned short*)out)[(size_t)node * 16 + f] = f2bfu(acc);
    else      ((float*)out)[(size_t)node * 16 + f] = acc;
}

// ---------- launch ----------
extern "C" void kernel_launch(void* const* d_in, const int* in_sizes, int n_in,
                              void* d_out, int out_size, void* d_ws, size_t ws_size,
                              hipStream_t stream) {
    const int*  edges = (const int*)d_in[0];
    const void* feat  = d_in[1];
    const void* W1    = d_in[2];
    const void* b1    = d_in[3];
    const void* W2    = d_in[4];
    const void* b2    = d_in[5];
    const void* W3    = d_in[6];
    const void* b3    = d_in[7];
    const void* Wfc   = d_in[8];
    const void* bfc   = d_in[9];

    const int E = in_sizes[0] / 2;
    const int N = in_sizes[1] / 128;
    const int* row = edges;
    const int* col = edges + E;

    const int B  = DIVUP(E, CHUNK);    // phase-A blocks (2048-edge chunks, full-grid resident)
    const int NB = DIVUP(N, 256);      // col buckets / phase-B blocks
    const int NBB = NB * B;            // scan length

    char* p = (char*)d_ws;
    int*   flag   = (int*)p;               p += 16;
    float* dinv   = (float*)p;             p += (size_t)N * 4;
    int*   cnt    = (int*)p;               p += (size_t)N * 4;
    int*   rowptr = (int*)p;               p += (size_t)N * 4;
    int*   csr    = (int*)p;               p += (size_t)E * 4;
    int*   part   = (int*)p;               p += (size_t)E * 4;   // packed 4B entries
    unsigned short* y  = (unsigned short*)p; p += (size_t)N * 64 * 2;  // gemm1 output
    unsigned short* y2 = (unsigned short*)p; p += (size_t)N * 32 * 2;  // fused gemm2 output
    unsigned short* y3 = (unsigned short*)p; p += (size_t)N * 16 * 2;  // fused gemm3 output
    unsigned short* f1 = (unsigned short*)p; p += (size_t)N * 64 * 2;
    unsigned short* f2 = (unsigned short*)p; p += (size_t)N * 32 * 2;
    int*   cntRB  = (int*)p;               p += (size_t)NBB * 4;
    int*   segoff = (int*)p;               p += (size_t)NBB * 4;
    int*   bsum   = (int*)p;

    // CSR build (also produces cnt, rowptr, dinv) — no global atomics
    parta_hist<<<B, 256, 0, stream>>>(col, cntRB, E, B, NB);
    const int nb = DIVUP(NBB, 1024);
    scan_block_sums<<<nb, 256, 0, stream>>>(cntRB, bsum, NBB);
    scan_bsum<<<1, 256, 0, stream>>>(bsum, nb, feat, flag);
    scan_final<<<nb, 256, 0, stream>>>(cntRB, bsum, segoff, NBB);
    parta_scatter<<<B, 256, 0, stream>>>(row, col, segoff, part, E, B, NB);
    csr_build<<<NB, 1024, 0, stream>>>(part, segoff, rowptr, cnt, dinv, csr, E, B, NB, N);

    // layer 1: 128 -> 64 (rows = 128B = full line, SH=0)
    gemm_mfma<128, 64, 0><<<DIVUP(N, 64), 256, 0, stream>>>(feat, W1, dinv, y, N, flag);
    // agg1 + fused gemm2 (64 -> 32)
    aggregate_gemm<64, 0, 32><<<DIVUP(N, 4), 256, 0, stream>>>(y, csr, rowptr, cnt, dinv,
                                                               b1, W2, f1, y2, N, flag);
    // agg2 + fused gemm3 (32 -> 16)
    aggregate_gemm<32, 1, 16><<<DIVUP(N, 8), 256, 0, stream>>>(y2, csr, rowptr, cnt, dinv,
                                                               b2, W3, f2, y3, N, flag);
    // agg3 + dense head
    aggregate3_head<<<DIVUP(N, 16), 256, 0, stream>>>(y3, csr, rowptr, cnt, dinv, b3,
                                                      f1, f2, Wfc, bfc, d_out, N, flag);
}

// Round 9
// 414.171 us; speedup vs baseline: 1.1851x; 1.1851x over previous
//
#include <hip/hip_runtime.h>
#include <hip/hip_bf16.h>

#define DIVUP(a, b) (((a) + (b) - 1) / (b))

typedef __attribute__((ext_vector_type(8))) short bf16x8;
typedef __attribute__((ext_vector_type(4))) float f32x4;

// ---------- helpers ----------
__device__ __forceinline__ float bf2f(unsigned short u) {
    union { unsigned int i; float f; } v;
    v.i = ((unsigned int)u) << 16;
    return v.f;
}
__device__ __forceinline__ unsigned short f2bfu(float x) {
    return __hip_bfloat16_raw(__float2bfloat16(x)).x;   // RNE
}
__device__ __forceinline__ float gload(const void* p, int i, int isbf) {
    return isbf ? bf2f(((const unsigned short*)p)[i]) : ((const float*)p)[i];
}

// ================= CSR build: counting sort, zero global atomics =================
// Round-13 lesson: direct global-atomic scatter = 300us (random 4B stores are
// ~64B HBM RMW each + serialized atomic-return chain). Keep bucketed sort.
// Round-15 lesson: shfl-based fused dots cost ~30cy/element serially — only
// fuse cross-lane dot products when shuffle count is O(16) (agg3_head), never
// O(64) (the reverted aggregate_gemm: +82us).
#define CHUNK 2048

__global__ void __launch_bounds__(256) parta_hist(const int* __restrict__ col,
                                                  int* __restrict__ cntRB,
                                                  int E, int B, int NB) {
    __shared__ int h[512];
    for (int i = threadIdx.x; i < NB; i += 256) h[i] = 0;
    __syncthreads();
    const int base = blockIdx.x * CHUNK;
#pragma unroll
    for (int k = 0; k < CHUNK / 256; ++k) {
        const int e = base + k * 256 + threadIdx.x;
        if (e < E) atomicAdd(&h[col[e] >> 8], 1);
    }
    __syncthreads();
    for (int i = threadIdx.x; i < NB; i += 256) cntRB[i * B + blockIdx.x] = h[i];
}

__global__ void __launch_bounds__(256) scan_block_sums(const int* __restrict__ cnt,
                                                       int* __restrict__ bsum, int n) {
    __shared__ int red[256];
    const int base = blockIdx.x * 1024;
    int s = 0;
    for (int i = threadIdx.x; i < 1024; i += 256) {
        const int idx = base + i;
        s += (idx < n) ? cnt[idx] : 0;
    }
    red[threadIdx.x] = s;
    __syncthreads();
    for (int off = 128; off > 0; off >>= 1) {
        if (threadIdx.x < off) red[threadIdx.x] += red[threadIdx.x + off];
        __syncthreads();
    }
    if (threadIdx.x == 0) bsum[blockIdx.x] = red[0];
}

// single-block exclusive scan with carry loop + folded dtype detection
__global__ void __launch_bounds__(256) scan_bsum(int* __restrict__ bsum, int nb,
                                                 const void* __restrict__ feat,
                                                 int* __restrict__ flag) {
    __shared__ int tmp[256];
    __shared__ int carry;
    __shared__ int dcnt;
    const int x = threadIdx.x;
    if (x == 0) { carry = 0; dcnt = 0; }
    __syncthreads();
    {   // dtype detect: plausible-bf16 heuristic over first 2048 halfwords
        const unsigned short* u = (const unsigned short*)feat;
        int c = 0;
#pragma unroll
        for (int rep = 0; rep < 4; ++rep) {
            const float v = fabsf(bf2f(u[x * 2 + rep * 512]));
            c += (v > 1e-4f && v < 10.0f) ? 1 : 0;
        }
        atomicAdd(&dcnt, c);
        __syncthreads();
        if (x == 0) *flag = (dcnt > 512) ? 1 : 0;
    }
    for (int base = 0; base < nb; base += 256) {
        const int idx = base + x;
        const int v = (idx < nb) ? bsum[idx] : 0;
        tmp[x] = v;
        __syncthreads();
        int val = v;
        for (int off = 1; off < 256; off <<= 1) {
            const int t = (x >= off) ? tmp[x - off] : 0;
            __syncthreads();
            val += t;
            tmp[x] = val;
            __syncthreads();
        }
        if (idx < nb) bsum[idx] = carry + val - v;   // exclusive
        __syncthreads();                              // all read carry first
        if (x == 255) carry += val;                   // chunk total
        __syncthreads();
    }
}

__global__ void __launch_bounds__(256) scan_final(const int* __restrict__ cnt,
                                                  const int* __restrict__ bsum,
                                                  int* __restrict__ outp, int n) {
    __shared__ int tsum[256];
    const int base = blockIdx.x * 1024;
    const int x = threadIdx.x;
    int v[4];
    int s = 0;
#pragma unroll
    for (int k = 0; k < 4; ++k) {
        const int idx = base + x * 4 + k;
        v[k] = (idx < n) ? cnt[idx] : 0;
        s += v[k];
    }
    tsum[x] = s;
    __syncthreads();
    int val = s;
    for (int off = 1; off < 256; off <<= 1) {
        const int t = (x >= off) ? tsum[x - off] : 0;
        __syncthreads();
        val += t;
        tsum[x] = val;
        __syncthreads();
    }
    int prefix = bsum[blockIdx.x] + (val - s);
#pragma unroll
    for (int k = 0; k < 4; ++k) {
        const int idx = base + x * 4 + k;
        if (idx < n) outp[idx] = prefix;
        prefix += v[k];
    }
}

__global__ void __launch_bounds__(256) parta_scatter(const int* __restrict__ row,
                                                     const int* __restrict__ col,
                                                     const int* __restrict__ seg_off,
                                                     int* __restrict__ part,
                                                     int E, int B, int NB) {
    __shared__ int cur[512];
    for (int i = threadIdx.x; i < NB; i += 256) cur[i] = seg_off[i * B + blockIdx.x];
    __syncthreads();
    const int base = blockIdx.x * CHUNK;
    int c[CHUNK / 256], r[CHUNK / 256];
#pragma unroll
    for (int k = 0; k < CHUNK / 256; ++k) {
        const int e = base + k * 256 + threadIdx.x;
        if (e < E) { c[k] = col[e]; r[k] = row[e]; }
    }
#pragma unroll
    for (int k = 0; k < CHUNK / 256; ++k) {
        const int e = base + k * 256 + threadIdx.x;
        if (e < E) {
            const int p = atomicAdd(&cur[c[k] >> 8], 1);
            part[p] = (c[k] & 255) | (r[k] << 8);   // 4B packed: low8=col-in-bucket
        }
    }
}

// Round-16: stage the bucket's part-segment in LDS once (avg 8192, cap 12288
// entries; Poisson max ~8.6K so fallback is for adversarial inputs only).
// Saves the second 12.8MB global pass; scatter reads come from LDS.
// 1024 threads (16 waves) — wave-capped at 2 blocks/CU either way.
// LDS: 12288*4 + 2*256*4 = 51200B < 64KB workgroup limit. `fits` is
// block-uniform (same seg_off loads in every thread) -> no barrier divergence.
#define SEG_CAP 12288
__global__ void __launch_bounds__(1024) csr_build(const int* __restrict__ part,
                                                  const int* __restrict__ seg_off,
                                                  int* __restrict__ rowptr,
                                                  int* __restrict__ cnt,
                                                  float* __restrict__ dinv,
                                                  int* __restrict__ csr,
                                                  int E, int B, int NB, int N) {
    __shared__ int spart[SEG_CAP];
    __shared__ int cl[256];
    __shared__ int sc[256];
    const int r   = blockIdx.x;
    const int c0  = r << 8;
    const int s0  = seg_off[(size_t)r * B];
    const int s1  = (r == NB - 1) ? E : seg_off[(size_t)(r + 1) * B];
    const int len = s1 - s0;
    const int x   = threadIdx.x;
    const bool fits = (len <= SEG_CAP);
    if (x < 256) cl[x] = 0;
    __syncthreads();
    if (fits) {
        for (int i = x; i < len; i += 1024) {
            const int pr = part[s0 + i];      // coalesced, single global pass
            spart[i] = pr;
            atomicAdd(&cl[pr & 255], 1);
        }
    } else {
        for (int i = s0 + x; i < s1; i += 1024)
            atomicAdd(&cl[part[i] & 255], 1);
    }
    __syncthreads();
    int v = 0, val = 0;
    if (x < 256) { v = cl[x]; sc[x] = v; val = v; }
    __syncthreads();
    for (int off = 1; off < 256; off <<= 1) {
        const int t = (x >= off && x < 256) ? sc[x - off] : 0;
        __syncthreads();
        if (x < 256) { val += t; sc[x] = val; }
        __syncthreads();
    }
    const int excl = val - v;
    if (x < 256) {
        const int c = c0 + x;
        if (c < N) {
            rowptr[c] = s0 + excl;
            cnt[c]    = v;
            dinv[c]   = rsqrtf((float)v + 1.0f);
        }
        cl[x] = s0 + excl;   // reuse as cursor
    }
    __syncthreads();
    if (fits) {
        for (int i = x; i < len; i += 1024) {
            const int pr = spart[i];
            const int p = atomicAdd(&cl[pr & 255], 1);
            csr[p] = (pr >> 8) << 7;
        }
    } else {
        for (int i = s0 + x; i < s1; i += 1024) {
            const int pr = part[i];
            const int p = atomicAdd(&cl[pr & 255], 1);
            csr[p] = (pr >> 8) << 7;   // row*128: byte offset template
        }
    }
}

// ================= MFMA GEMM: y = bf16((x @ W) * dinv[node]) =================
// Block = 4 waves x 16 nodes. Verified layouts (cdna docs m89/m91/m120):
//   A[m=lane&15][k=quad*8+j]   <- loaded straight from global (row node, k-chunk)
//   B[k=quad*8+j][n=lane&15]   <- ds_read_b128 from transposed Wt[n][k]
//   D col=lane&15, row=quad*4+reg
template<int F_IN, int F_OUT, int XMODE>
__global__ void __launch_bounds__(256) gemm_mfma(const void* __restrict__ x,
                                                 const void* __restrict__ W,
                                                 const float* __restrict__ dinv,
                                                 unsigned short* __restrict__ y,
                                                 int n, const int* __restrict__ flag) {
    constexpr int KS = F_IN / 32;        // k-slices
    constexpr int NT = F_OUT / 16;       // f-tiles
    constexpr int WPAD = F_IN + 8;       // +16B row pad vs bank conflicts
    const int isbf = *flag;
    __shared__ unsigned short Wt[F_OUT * WPAD];

    for (int i = threadIdx.x; i < F_IN * F_OUT; i += 256) {
        const int k = i / F_OUT, nn = i % F_OUT;
        Wt[nn * WPAD + k] = f2bfu(gload(W, i, isbf));
    }
    __syncthreads();

    const int lane = threadIdx.x & 63;
    const int wid  = threadIdx.x >> 6;
    const int m    = lane & 15;
    const int quad = lane >> 4;
    const int nodeA = blockIdx.x * 64 + wid * 16 + m;

    bf16x8 afr[KS];
    if (nodeA < n) {
        if (XMODE == 1 || isbf) {
            const unsigned short* xr = (const unsigned short*)x + (size_t)nodeA * F_IN;
#pragma unroll
            for (int s = 0; s < KS; ++s)
                afr[s] = *(const bf16x8*)(xr + s * 32 + quad * 8);
        } else {
            const float* xr = (const float*)x + (size_t)nodeA * F_IN;
#pragma unroll
            for (int s = 0; s < KS; ++s) {
                const float4 v0 = *(const float4*)(xr + s * 32 + quad * 8);
                const float4 v1 = *(const float4*)(xr + s * 32 + quad * 8 + 4);
                bf16x8 a;
                a[0] = (short)f2bfu(v0.x); a[1] = (short)f2bfu(v0.y);
                a[2] = (short)f2bfu(v0.z); a[3] = (short)f2bfu(v0.w);
                a[4] = (short)f2bfu(v1.x); a[5] = (short)f2bfu(v1.y);
                a[6] = (short)f2bfu(v1.z); a[7] = (short)f2bfu(v1.w);
                afr[s] = a;
            }
        }
    } else {
#pragma unroll
        for (int s = 0; s < KS; ++s) afr[s] = (bf16x8)(short)0;
    }

    f32x4 acc[NT];
#pragma unroll
    for (int t = 0; t < NT; ++t) acc[t] = (f32x4)0.f;

#pragma unroll
    for (int t = 0; t < NT; ++t) {
#pragma unroll
        for (int s = 0; s < KS; ++s) {
            const bf16x8 bfr = *(const bf16x8*)(Wt + (t * 16 + m) * WPAD + s * 32 + quad * 8);
            acc[t] = __builtin_amdgcn_mfma_f32_16x16x32_bf16(afr[s], bfr, acc[t], 0, 0, 0);
        }
    }

#pragma unroll
    for (int r = 0; r < 4; ++r) {
        const int ng = blockIdx.x * 64 + wid * 16 + quad * 4 + r;
        if (ng < n) {
            const float scl = dinv[ng];
#pragma unroll
            for (int t = 0; t < NT; ++t) {
                const int f = t * 16 + m;
                y[(size_t)ng * F_OUT + f] = f2bfu(acc[t][r] * scl);
            }
        }
    }
}

// ---------- aggregate core: node-group = 4 edge-slots x L4 lanes, ushort4 ----------
template<int F, int SH>
__device__ __forceinline__ void agg_core(const unsigned short* __restrict__ y,
                                         const int* __restrict__ csr,
                                         int beg, int deg, int e, int ub,
                                         float4& a) {
    const char* yb = (const char*)y;
    int j = 0;
    for (; j + 32 <= deg; j += 32) {
        int o[8];
#pragma unroll
        for (int k = 0; k < 8; ++k) o[k] = csr[beg + j + e + 4 * k] >> SH;
        float4 v[8];
#pragma unroll
        for (int k = 0; k < 8; ++k) {
            const ushort4 t = *(const ushort4*)(yb + o[k] + ub);
            v[k] = make_float4(bf2f(t.x), bf2f(t.y), bf2f(t.z), bf2f(t.w));
        }
#pragma unroll
        for (int s = 1; s < 8; s <<= 1)
#pragma unroll
            for (int k = 0; k < 8; k += 2 * s) {
                v[k].x += v[k + s].x; v[k].y += v[k + s].y;
                v[k].z += v[k + s].z; v[k].w += v[k + s].w;
            }
        a.x += v[0].x; a.y += v[0].y; a.z += v[0].z; a.w += v[0].w;
    }
    if (j + 16 <= deg) {
        int o[4];
#pragma unroll
        for (int k = 0; k < 4; ++k) o[k] = csr[beg + j + e + 4 * k] >> SH;
        float4 v[4];
#pragma unroll
        for (int k = 0; k < 4; ++k) {
            const ushort4 t = *(const ushort4*)(yb + o[k] + ub);
            v[k] = make_float4(bf2f(t.x), bf2f(t.y), bf2f(t.z), bf2f(t.w));
        }
#pragma unroll
        for (int s = 1; s < 4; s <<= 1)
#pragma unroll
            for (int k = 0; k < 4; k += 2 * s) {
                v[k].x += v[k + s].x; v[k].y += v[k + s].y;
                v[k].z += v[k + s].z; v[k].w += v[k + s].w;
            }
        a.x += v[0].x; a.y += v[0].y; a.z += v[0].z; a.w += v[0].w;
        j += 16;
    }
    if (j + 8 <= deg) {
        int o0 = csr[beg + j + e] >> SH;
        int o1 = csr[beg + j + e + 4] >> SH;
        const ushort4 t0 = *(const ushort4*)(yb + o0 + ub);
        const ushort4 t1 = *(const ushort4*)(yb + o1 + ub);
        a.x += bf2f(t0.x) + bf2f(t1.x); a.y += bf2f(t0.y) + bf2f(t1.y);
        a.z += bf2f(t0.z) + bf2f(t1.z); a.w += bf2f(t0.w) + bf2f(t1.w);
        j += 8;
    }
    for (; j < deg; j += 4) {
        if (j + e < deg) {
            const int o = csr[beg + j + e] >> SH;
            const ushort4 t = *(const ushort4*)(yb + o + ub);
            a.x += bf2f(t.x); a.y += bf2f(t.y); a.z += bf2f(t.z); a.w += bf2f(t.w);
        }
    }
}

template<int F, int SH>
__global__ void __launch_bounds__(256) aggregate(const unsigned short* __restrict__ y,
                                                 const int* __restrict__ csr,
                                                 const int* __restrict__ rowptr,
                                                 const int* __restrict__ cnt,
                                                 const float* __restrict__ dinv,
                                                 const void* __restrict__ b,
                                                 unsigned short* __restrict__ out,
                                                 int n, const int* __restrict__ flag) {
    const int isbf = *flag;
    constexpr int L4  = F / 4;        // lanes per row (ushort4 each)
    constexpr int GL  = 4 * L4;       // lanes per node-group (4 edge slots)
    constexpr int NPW = 64 / GL;      // nodes per wave
    constexpr int LGL = (GL == 64) ? 6 : (GL == 32) ? 5 : 4;
    const int lane = threadIdx.x & 63;
    const int wv   = (blockIdx.x * 256 + threadIdx.x) >> 6;
    const int node = wv * NPW + (lane >> LGL);
    if (node >= n) return;
    const int g  = lane & (GL - 1);
    const int e  = g / L4;            // edge slot 0..3
    const int u  = g % L4;            // feature quad
    const int ub = u * 8;             // byte offset of this lane's ushort4

    float4 a = make_float4(0.f, 0.f, 0.f, 0.f);
    agg_core<F, SH>(y, csr, rowptr[node], cnt[node], e, ub, a);

    // reduce across the 4 edge-slots (partners in same node-group: active)
#pragma unroll
    for (int mm = L4; mm < GL; mm <<= 1) {
        a.x += __shfl_xor(a.x, mm, 64); a.y += __shfl_xor(a.y, mm, 64);
        a.z += __shfl_xor(a.z, mm, 64); a.w += __shfl_xor(a.w, mm, 64);
    }

    if (g < L4) {
        const ushort4 t = *(const ushort4*)((const char*)y + (size_t)node * (F * 2) + ub);
        const float d = dinv[node];
        float4 r;
        r.x = fmaxf(d * (a.x + bf2f(t.x)) + gload(b, 4 * u + 0, isbf), 0.f);
        r.y = fmaxf(d * (a.y + bf2f(t.y)) + gload(b, 4 * u + 1, isbf), 0.f);
        r.z = fmaxf(d * (a.z + bf2f(t.z)) + gload(b, 4 * u + 2, isbf), 0.f);
        r.w = fmaxf(d * (a.w + bf2f(t.w)) + gload(b, 4 * u + 3, isbf), 0.f);
        ushort4 w;
        w.x = f2bfu(r.x); w.y = f2bfu(r.y); w.z = f2bfu(r.z); w.w = f2bfu(r.w);
        *(ushort4*)(out + (size_t)node * F + 4 * u) = w;
    }
}

// ---------- layer-3 aggregate fused with dense head ----------
__global__ void __launch_bounds__(256) aggregate3_head(const unsigned short* __restrict__ y,
                                                       const int* __restrict__ csr,
                                                       const int* __restrict__ rowptr,
                                                       const int* __restrict__ cnt,
                                                       const float* __restrict__ dinv,
                                                       const void* __restrict__ b3,
                                                       const unsigned short* __restrict__ f1,
                                                       const unsigned short* __restrict__ f2,
                                                       const void* __restrict__ Wfc,
                                                       const void* __restrict__ bfc,
                                                       void* __restrict__ out,
                                                       int n, const int* __restrict__ flag) {
    const int isbf = *flag;
    __shared__ float Ws[112 * 16];
    for (int i = threadIdx.x; i < 112 * 16; i += 256) Ws[i] = gload(Wfc, i, isbf);
    __syncthreads();                              // before ANY return

    const int lane = threadIdx.x & 63;
    const int wv   = (blockIdx.x * 256 + threadIdx.x) >> 6;
    const int node = wv * 4 + (lane >> 4);        // F=16: GL=16, NPW=4
    if (node >= n) return;
    const int g  = lane & 15;
    const int e  = g >> 2;
    const int u  = g & 3;
    const int ub = u * 8;

    float4 a = make_float4(0.f, 0.f, 0.f, 0.f);
    agg_core<16, 2>(y, csr, rowptr[node], cnt[node], e, ub, a);

#pragma unroll
    for (int mm = 4; mm < 16; mm <<= 1) {
        a.x += __shfl_xor(a.x, mm, 64); a.y += __shfl_xor(a.y, mm, 64);
        a.z += __shfl_xor(a.z, mm, 64); a.w += __shfl_xor(a.w, mm, 64);
    }

    // epilogue in ALL lanes (every lane holds the quad for u = g&3)
    float4 r;
    {
        const ushort4 t = *(const ushort4*)((const char*)y + (size_t)node * 32 + ub);
        const float d = dinv[node];
        r.x = fmaxf(d * (a.x + bf2f(t.x)) + gload(b3, 4 * u + 0, isbf), 0.f);
        r.y = fmaxf(d * (a.y + bf2f(t.y)) + gload(b3, 4 * u + 1, isbf), 0.f);
        r.z = fmaxf(d * (a.z + bf2f(t.z)) + gload(b3, 4 * u + 2, isbf), 0.f);
        r.w = fmaxf(d * (a.w + bf2f(t.w)) + gload(b3, 4 * u + 3, isbf), 0.f);
    }

    // ---- head: lane computes output feature f = g for its group's node ----
    const int f = g;
    float acc = gload(bfc, f, isbf);
    const unsigned short* x1 = f1 + (size_t)node * 64;
#pragma unroll
    for (int k4 = 0; k4 < 16; ++k4) {
        const ushort4 xu = *(const ushort4*)(x1 + 4 * k4);
        acc = fmaf(bf2f(xu.x), Ws[(4 * k4 + 0) * 16 + f], acc);
        acc = fmaf(bf2f(xu.y), Ws[(4 * k4 + 1) * 16 + f], acc);
        acc = fmaf(bf2f(xu.z), Ws[(4 * k4 + 2) * 16 + f], acc);
        acc = fmaf(bf2f(xu.w), Ws[(4 * k4 + 3) * 16 + f], acc);
    }
    const unsigned short* x2 = f2 + (size_t)node * 32;
#pragma unroll
    for (int k4 = 0; k4 < 8; ++k4) {
        const ushort4 xu = *(const ushort4*)(x2 + 4 * k4);
        acc = fmaf(bf2f(xu.x), Ws[(64 + 4 * k4 + 0) * 16 + f], acc);
        acc = fmaf(bf2f(xu.y), Ws[(64 + 4 * k4 + 1) * 16 + f], acc);
        acc = fmaf(bf2f(xu.z), Ws[(64 + 4 * k4 + 2) * 16 + f], acc);
        acc = fmaf(bf2f(xu.w), Ws[(64 + 4 * k4 + 3) * 16 + f], acc);
    }
    // f3 via intra-group shuffles: src lane (lane&~15)+(k3>>2) holds comp k3&3
    const int gbase = lane & ~15;
#pragma unroll
    for (int k3 = 0; k3 < 16; k3 += 4) {
        const int src = gbase + (k3 >> 2);
        acc = fmaf(__shfl(r.x, src, 64), Ws[(96 + k3 + 0) * 16 + f], acc);
        acc = fmaf(__shfl(r.y, src, 64), Ws[(96 + k3 + 1) * 16 + f], acc);
        acc = fmaf(__shfl(r.z, src, 64), Ws[(96 + k3 + 2) * 16 + f], acc);
        acc = fmaf(__shfl(r.w, src, 64), Ws[(96 + k3 + 3) * 16 + f], acc);
    }
    acc = fmaxf(acc, 0.f);
    if (isbf) ((unsigned short*)out)[(size_t)node * 16 + f] = f2bfu(acc);
    else      ((float*)out)[(size_t)node * 16 + f] = acc;
}

// ---------- launch ----------
extern "C" void kernel_launch(void* const* d_in, const int* in_sizes, int n_in,
                              void* d_out, int out_size, void* d_ws, size_t ws_size,
                              hipStream_t stream) {
    const int*  edges = (const int*)d_in[0];
    const void* feat  = d_in[1];
    const void* W1    = d_in[2];
    const void* b1    = d_in[3];
    const void* W2    = d_in[4];
    const void* b2    = d_in[5];
    const void* W3    = d_in[6];
    const void* b3    = d_in[7];
    const void* Wfc   = d_in[8];
    const void* bfc   = d_in[9];

    const int E = in_sizes[0] / 2;
    const int N = in_sizes[1] / 128;
    const int* row = edges;
    const int* col = edges + E;

    const int B  = DIVUP(E, CHUNK);    // phase-A blocks (2048-edge chunks, full-grid resident)
    const int NB = DIVUP(N, 256);      // col buckets / phase-B blocks
    const int NBB = NB * B;            // scan length

    char* p = (char*)d_ws;
    int*   flag   = (int*)p;               p += 16;
    float* dinv   = (float*)p;             p += (size_t)N * 4;
    int*   cnt    = (int*)p;               p += (size_t)N * 4;
    int*   rowptr = (int*)p;               p += (size_t)N * 4;
    int*   csr    = (int*)p;               p += (size_t)E * 4;
    int*   part   = (int*)p;               p += (size_t)E * 4;   // packed 4B entries
    unsigned short* y  = (unsigned short*)p; p += (size_t)N * 64 * 2;  // gemm output (max 64 feat)
    unsigned short* f1 = (unsigned short*)p; p += (size_t)N * 64 * 2;
    unsigned short* f2 = (unsigned short*)p; p += (size_t)N * 32 * 2;
    int*   cntRB  = (int*)p;               p += (size_t)NBB * 4;
    int*   segoff = (int*)p;               p += (size_t)NBB * 4;
    int*   bsum   = (int*)p;

    // CSR build (also produces cnt, rowptr, dinv) — no global atomics
    parta_hist<<<B, 256, 0, stream>>>(col, cntRB, E, B, NB);
    const int nb = DIVUP(NBB, 1024);
    scan_block_sums<<<nb, 256, 0, stream>>>(cntRB, bsum, NBB);
    scan_bsum<<<1, 256, 0, stream>>>(bsum, nb, feat, flag);
    scan_final<<<nb, 256, 0, stream>>>(cntRB, bsum, segoff, NBB);
    parta_scatter<<<B, 256, 0, stream>>>(row, col, segoff, part, E, B, NB);
    csr_build<<<NB, 1024, 0, stream>>>(part, segoff, rowptr, cnt, dinv, csr, E, B, NB, N);

    // layer 1: 128 -> 64, single full-width pass (rows = 128B = full line, SH=0)
    gemm_mfma<128, 64, 0><<<DIVUP(N, 64), 256, 0, stream>>>(feat, W1, dinv, y, N, flag);
    aggregate<64, 0><<<DIVUP(N, 4), 256, 0, stream>>>(y, csr, rowptr, cnt, dinv, b1, f1, N, flag);

    // layer 2: 64 -> 32  (2 nodes/wave)
    gemm_mfma<64, 32, 1><<<DIVUP(N, 64), 256, 0, stream>>>(f1, W2, dinv, y, N, flag);
    aggregate<32, 1><<<DIVUP(N, 8), 256, 0, stream>>>(y, csr, rowptr, cnt, dinv, b2, f2, N, flag);

    // layer 3: 32 -> 16, aggregate + dense head fused (4 nodes/wave)
    gemm_mfma<32, 16, 1><<<DIVUP(N, 64), 256, 0, stream>>>(f2, W3, dinv, y, N, flag);
    aggregate3_head<<<DIVUP(N, 16), 256, 0, stream>>>(y, csr, rowptr, cnt, dinv, b3,
                                                      f1, f2, Wfc, bfc, d_out, N, flag);
}

// Round 10
// 398.450 us; speedup vs baseline: 1.2319x; 1.0395x over previous
//
#include <hip/hip_runtime.h>
#include <hip/hip_bf16.h>

#define DIVUP(a, b) (((a) + (b) - 1) / (b))

typedef __attribute__((ext_vector_type(8))) short bf16x8;
typedef __attribute__((ext_vector_type(4))) float f32x4;

// ---------- helpers ----------
__device__ __forceinline__ float bf2f(unsigned short u) {
    union { unsigned int i; float f; } v;
    v.i = ((unsigned int)u) << 16;
    return v.f;
}
__device__ __forceinline__ unsigned short f2bfu(float x) {
    return __hip_bfloat16_raw(__float2bfloat16(x)).x;   // RNE
}
__device__ __forceinline__ float gload(const void* p, int i, int isbf) {
    return isbf ? bf2f(((const unsigned short*)p)[i]) : ((const float*)p)[i];
}

// ================= CSR build: counting sort, zero global atomics =================
// Round-13 lesson: direct global-atomic scatter = 300us (random 4B stores are
// ~64B HBM RMW each + serialized atomic-return chain). Keep bucketed sort.
// Round-15 lesson: shfl-based fused dots cost ~30cy/element serially — only
// fuse cross-lane dot products when shuffle count is O(16) (agg3_head), never
// O(64) (the reverted aggregate_gemm: +82us).
// Round-17: CHUNK 2048->8192 @1024 threads. Residency kept (391 blocks x 16
// waves = 6256 waves, ~76% of chip) — the round-8 lever was waves-in-flight,
// not block count. NBB 611K->153K: hist's strided 4B cntRB scatter loses 4x
// write-amplification (39->9.8MB) and scans stream 4x less.
#define CHUNK 8192

__global__ void __launch_bounds__(1024) parta_hist(const int* __restrict__ col,
                                                   int* __restrict__ cntRB,
                                                   int E, int B, int NB) {
    __shared__ int h[512];
    for (int i = threadIdx.x; i < NB; i += 1024) h[i] = 0;
    __syncthreads();
    const int base = blockIdx.x * CHUNK;
#pragma unroll
    for (int k = 0; k < CHUNK / 1024; ++k) {
        const int e = base + k * 1024 + threadIdx.x;
        if (e < E) atomicAdd(&h[col[e] >> 8], 1);
    }
    __syncthreads();
    for (int i = threadIdx.x; i < NB; i += 1024) cntRB[i * B + blockIdx.x] = h[i];
}

__global__ void __launch_bounds__(256) scan_block_sums(const int* __restrict__ cnt,
                                                       int* __restrict__ bsum, int n) {
    __shared__ int red[256];
    const int base = blockIdx.x * 1024;
    int s = 0;
    for (int i = threadIdx.x; i < 1024; i += 256) {
        const int idx = base + i;
        s += (idx < n) ? cnt[idx] : 0;
    }
    red[threadIdx.x] = s;
    __syncthreads();
    for (int off = 128; off > 0; off >>= 1) {
        if (threadIdx.x < off) red[threadIdx.x] += red[threadIdx.x + off];
        __syncthreads();
    }
    if (threadIdx.x == 0) bsum[blockIdx.x] = red[0];
}

// single-block exclusive scan with carry loop + folded dtype detection
__global__ void __launch_bounds__(256) scan_bsum(int* __restrict__ bsum, int nb,
                                                 const void* __restrict__ feat,
                                                 int* __restrict__ flag) {
    __shared__ int tmp[256];
    __shared__ int carry;
    __shared__ int dcnt;
    const int x = threadIdx.x;
    if (x == 0) { carry = 0; dcnt = 0; }
    __syncthreads();
    {   // dtype detect: plausible-bf16 heuristic over first 2048 halfwords
        const unsigned short* u = (const unsigned short*)feat;
        int c = 0;
#pragma unroll
        for (int rep = 0; rep < 4; ++rep) {
            const float v = fabsf(bf2f(u[x * 2 + rep * 512]));
            c += (v > 1e-4f && v < 10.0f) ? 1 : 0;
        }
        atomicAdd(&dcnt, c);
        __syncthreads();
        if (x == 0) *flag = (dcnt > 512) ? 1 : 0;
    }
    for (int base = 0; base < nb; base += 256) {
        const int idx = base + x;
        const int v = (idx < nb) ? bsum[idx] : 0;
        tmp[x] = v;
        __syncthreads();
        int val = v;
        for (int off = 1; off < 256; off <<= 1) {
            const int t = (x >= off) ? tmp[x - off] : 0;
            __syncthreads();
            val += t;
            tmp[x] = val;
            __syncthreads();
        }
        if (idx < nb) bsum[idx] = carry + val - v;   // exclusive
        __syncthreads();                              // all read carry first
        if (x == 255) carry += val;                   // chunk total
        __syncthreads();
    }
}

__global__ void __launch_bounds__(256) scan_final(const int* __restrict__ cnt,
                                                  const int* __restrict__ bsum,
                                                  int* __restrict__ outp, int n) {
    __shared__ int tsum[256];
    const int base = blockIdx.x * 1024;
    const int x = threadIdx.x;
    int v[4];
    int s = 0;
#pragma unroll
    for (int k = 0; k < 4; ++k) {
        const int idx = base + x * 4 + k;
        v[k] = (idx < n) ? cnt[idx] : 0;
        s += v[k];
    }
    tsum[x] = s;
    __syncthreads();
    int val = s;
    for (int off = 1; off < 256; off <<= 1) {
        const int t = (x >= off) ? tsum[x - off] : 0;
        __syncthreads();
        val += t;
        tsum[x] = val;
        __syncthreads();
    }
    int prefix = bsum[blockIdx.x] + (val - s);
#pragma unroll
    for (int k = 0; k < 4; ++k) {
        const int idx = base + x * 4 + k;
        if (idx < n) outp[idx] = prefix;
        prefix += v[k];
    }
}

__global__ void __launch_bounds__(1024) parta_scatter(const int* __restrict__ row,
                                                      const int* __restrict__ col,
                                                      const int* __restrict__ seg_off,
                                                      int* __restrict__ part,
                                                      int E, int B, int NB) {
    __shared__ int cur[512];
    for (int i = threadIdx.x; i < NB; i += 1024) cur[i] = seg_off[i * B + blockIdx.x];
    __syncthreads();
    const int base = blockIdx.x * CHUNK;
    int c[CHUNK / 1024], r[CHUNK / 1024];
#pragma unroll
    for (int k = 0; k < CHUNK / 1024; ++k) {
        const int e = base + k * 1024 + threadIdx.x;
        if (e < E) { c[k] = col[e]; r[k] = row[e]; }
    }
#pragma unroll
    for (int k = 0; k < CHUNK / 1024; ++k) {
        const int e = base + k * 1024 + threadIdx.x;
        if (e < E) {
            const int p = atomicAdd(&cur[c[k] >> 8], 1);
            part[p] = (c[k] & 255) | (r[k] << 8);   // 4B packed: low8=col-in-bucket
        }
    }
}

// Round-16: stage the bucket's part-segment in LDS once (avg 8192, cap 12288
// entries; Poisson max ~8.6K so fallback is for adversarial inputs only).
// Saves the second 12.8MB global pass; scatter reads come from LDS.
// 1024 threads (16 waves). LDS: 12288*4 + 2*256*4 = 51200B < 64KB limit.
// `fits` is block-uniform -> no barrier divergence.
#define SEG_CAP 12288
__global__ void __launch_bounds__(1024) csr_build(const int* __restrict__ part,
                                                  const int* __restrict__ seg_off,
                                                  int* __restrict__ rowptr,
                                                  int* __restrict__ cnt,
                                                  float* __restrict__ dinv,
                                                  int* __restrict__ csr,
                                                  int E, int B, int NB, int N) {
    __shared__ int spart[SEG_CAP];
    __shared__ int cl[256];
    __shared__ int sc[256];
    const int r   = blockIdx.x;
    const int c0  = r << 8;
    const int s0  = seg_off[(size_t)r * B];
    const int s1  = (r == NB - 1) ? E : seg_off[(size_t)(r + 1) * B];
    const int len = s1 - s0;
    const int x   = threadIdx.x;
    const bool fits = (len <= SEG_CAP);
    if (x < 256) cl[x] = 0;
    __syncthreads();
    if (fits) {
        for (int i = x; i < len; i += 1024) {
            const int pr = part[s0 + i];      // coalesced, single global pass
            spart[i] = pr;
            atomicAdd(&cl[pr & 255], 1);
        }
    } else {
        for (int i = s0 + x; i < s1; i += 1024)
            atomicAdd(&cl[part[i] & 255], 1);
    }
    __syncthreads();
    int v = 0, val = 0;
    if (x < 256) { v = cl[x]; sc[x] = v; val = v; }
    __syncthreads();
    for (int off = 1; off < 256; off <<= 1) {
        const int t = (x >= off && x < 256) ? sc[x - off] : 0;
        __syncthreads();
        if (x < 256) { val += t; sc[x] = val; }
        __syncthreads();
    }
    const int excl = val - v;
    if (x < 256) {
        const int c = c0 + x;
        if (c < N) {
            rowptr[c] = s0 + excl;
            cnt[c]    = v;
            dinv[c]   = rsqrtf((float)v + 1.0f);
        }
        cl[x] = s0 + excl;   // reuse as cursor
    }
    __syncthreads();
    if (fits) {
        for (int i = x; i < len; i += 1024) {
            const int pr = spart[i];
            const int p = atomicAdd(&cl[pr & 255], 1);
            csr[p] = (pr >> 8) << 7;
        }
    } else {
        for (int i = s0 + x; i < s1; i += 1024) {
            const int pr = part[i];
            const int p = atomicAdd(&cl[pr & 255], 1);
            csr[p] = (pr >> 8) << 7;   // row*128: byte offset template
        }
    }
}

// ================= MFMA GEMM: y = bf16((x @ W) * dinv[node]) =================
// Block = 4 waves x 16 nodes. Verified layouts (cdna docs m89/m91/m120):
//   A[m=lane&15][k=quad*8+j]   <- loaded straight from global (row node, k-chunk)
//   B[k=quad*8+j][n=lane&15]   <- ds_read_b128 from transposed Wt[n][k]
//   D col=lane&15, row=quad*4+reg
template<int F_IN, int F_OUT, int XMODE>
__global__ void __launch_bounds__(256) gemm_mfma(const void* __restrict__ x,
                                                 const void* __restrict__ W,
                                                 const float* __restrict__ dinv,
                                                 unsigned short* __restrict__ y,
                                                 int n, const int* __restrict__ flag) {
    constexpr int KS = F_IN / 32;        // k-slices
    constexpr int NT = F_OUT / 16;       // f-tiles
    constexpr int WPAD = F_IN + 8;       // +16B row pad vs bank conflicts
    const int isbf = *flag;
    __shared__ unsigned short Wt[F_OUT * WPAD];

    for (int i = threadIdx.x; i < F_IN * F_OUT; i += 256) {
        const int k = i / F_OUT, nn = i % F_OUT;
        Wt[nn * WPAD + k] = f2bfu(gload(W, i, isbf));
    }
    __syncthreads();

    const int lane = threadIdx.x & 63;
    const int wid  = threadIdx.x >> 6;
    const int m    = lane & 15;
    const int quad = lane >> 4;
    const int nodeA = blockIdx.x * 64 + wid * 16 + m;

    bf16x8 afr[KS];
    if (nodeA < n) {
        if (XMODE == 1 || isbf) {
            const unsigned short* xr = (const unsigned short*)x + (size_t)nodeA * F_IN;
#pragma unroll
            for (int s = 0; s < KS; ++s)
                afr[s] = *(const bf16x8*)(xr + s * 32 + quad * 8);
        } else {
            const float* xr = (const float*)x + (size_t)nodeA * F_IN;
#pragma unroll
            for (int s = 0; s < KS; ++s) {
                const float4 v0 = *(const float4*)(xr + s * 32 + quad * 8);
                const float4 v1 = *(const float4*)(xr + s * 32 + quad * 8 + 4);
                bf16x8 a;
                a[0] = (short)f2bfu(v0.x); a[1] = (short)f2bfu(v0.y);
                a[2] = (short)f2bfu(v0.z); a[3] = (short)f2bfu(v0.w);
                a[4] = (short)f2bfu(v1.x); a[5] = (short)f2bfu(v1.y);
                a[6] = (short)f2bfu(v1.z); a[7] = (short)f2bfu(v1.w);
                afr[s] = a;
            }
        }
    } else {
#pragma unroll
        for (int s = 0; s < KS; ++s) afr[s] = (bf16x8)(short)0;
    }

    f32x4 acc[NT];
#pragma unroll
    for (int t = 0; t < NT; ++t) acc[t] = (f32x4)0.f;

#pragma unroll
    for (int t = 0; t < NT; ++t) {
#pragma unroll
        for (int s = 0; s < KS; ++s) {
            const bf16x8 bfr = *(const bf16x8*)(Wt + (t * 16 + m) * WPAD + s * 32 + quad * 8);
            acc[t] = __builtin_amdgcn_mfma_f32_16x16x32_bf16(afr[s], bfr, acc[t], 0, 0, 0);
        }
    }

#pragma unroll
    for (int r = 0; r < 4; ++r) {
        const int ng = blockIdx.x * 64 + wid * 16 + quad * 4 + r;
        if (ng < n) {
            const float scl = dinv[ng];
#pragma unroll
            for (int t = 0; t < NT; ++t) {
                const int f = t * 16 + m;
                y[(size_t)ng * F_OUT + f] = f2bfu(acc[t][r] * scl);
            }
        }
    }
}

// ---------- aggregate core: node-group = 4 edge-slots x L4 lanes, ushort4 ----------
template<int F, int SH>
__device__ __forceinline__ void agg_core(const unsigned short* __restrict__ y,
                                         const int* __restrict__ csr,
                                         int beg, int deg, int e, int ub,
                                         float4& a) {
    const char* yb = (const char*)y;
    int j = 0;
    for (; j + 32 <= deg; j += 32) {
        int o[8];
#pragma unroll
        for (int k = 0; k < 8; ++k) o[k] = csr[beg + j + e + 4 * k] >> SH;
        float4 v[8];
#pragma unroll
        for (int k = 0; k < 8; ++k) {
            const ushort4 t = *(const ushort4*)(yb + o[k] + ub);
            v[k] = make_float4(bf2f(t.x), bf2f(t.y), bf2f(t.z), bf2f(t.w));
        }
#pragma unroll
        for (int s = 1; s < 8; s <<= 1)
#pragma unroll
            for (int k = 0; k < 8; k += 2 * s) {
                v[k].x += v[k + s].x; v[k].y += v[k + s].y;
                v[k].z += v[k + s].z; v[k].w += v[k + s].w;
            }
        a.x += v[0].x; a.y += v[0].y; a.z += v[0].z; a.w += v[0].w;
    }
    if (j + 16 <= deg) {
        int o[4];
#pragma unroll
        for (int k = 0; k < 4; ++k) o[k] = csr[beg + j + e + 4 * k] >> SH;
        float4 v[4];
#pragma unroll
        for (int k = 0; k < 4; ++k) {
            const ushort4 t = *(const ushort4*)(yb + o[k] + ub);
            v[k] = make_float4(bf2f(t.x), bf2f(t.y), bf2f(t.z), bf2f(t.w));
        }
#pragma unroll
        for (int s = 1; s < 4; s <<= 1)
#pragma unroll
            for (int k = 0; k < 4; k += 2 * s) {
                v[k].x += v[k + s].x; v[k].y += v[k + s].y;
                v[k].z += v[k + s].z; v[k].w += v[k + s].w;
            }
        a.x += v[0].x; a.y += v[0].y; a.z += v[0].z; a.w += v[0].w;
        j += 16;
    }
    if (j + 8 <= deg) {
        int o0 = csr[beg + j + e] >> SH;
        int o1 = csr[beg + j + e + 4] >> SH;
        const ushort4 t0 = *(const ushort4*)(yb + o0 + ub);
        const ushort4 t1 = *(const ushort4*)(yb + o1 + ub);
        a.x += bf2f(t0.x) + bf2f(t1.x); a.y += bf2f(t0.y) + bf2f(t1.y);
        a.z += bf2f(t0.z) + bf2f(t1.z); a.w += bf2f(t0.w) + bf2f(t1.w);
        j += 8;
    }
    for (; j < deg; j += 4) {
        if (j + e < deg) {
            const int o = csr[beg + j + e] >> SH;
            const ushort4 t = *(const ushort4*)(yb + o + ub);
            a.x += bf2f(t.x); a.y += bf2f(t.y); a.z += bf2f(t.z); a.w += bf2f(t.w);
        }
    }
}

template<int F, int SH>
__global__ void __launch_bounds__(256) aggregate(const unsigned short* __restrict__ y,
                                                 const int* __restrict__ csr,
                                                 const int* __restrict__ rowptr,
                                                 const int* __restrict__ cnt,
                                                 const float* __restrict__ dinv,
                                                 const void* __restrict__ b,
                                                 unsigned short* __restrict__ out,
                                                 int n, const int* __restrict__ flag) {
    const int isbf = *flag;
    constexpr int L4  = F / 4;        // lanes per row (ushort4 each)
    constexpr int GL  = 4 * L4;       // lanes per node-group (4 edge slots)
    constexpr int NPW = 64 / GL;      // nodes per wave
    constexpr int LGL = (GL == 64) ? 6 : (GL == 32) ? 5 : 4;
    const int lane = threadIdx.x & 63;
    const int wv   = (blockIdx.x * 256 + threadIdx.x) >> 6;
    const int node = wv * NPW + (lane >> LGL);
    if (node >= n) return;
    const int g  = lane & (GL - 1);
    const int e  = g / L4;            // edge slot 0..3
    const int u  = g % L4;            // feature quad
    const int ub = u * 8;             // byte offset of this lane's ushort4

    float4 a = make_float4(0.f, 0.f, 0.f, 0.f);
    agg_core<F, SH>(y, csr, rowptr[node], cnt[node], e, ub, a);

    // reduce across the 4 edge-slots (partners in same node-group: active)
#pragma unroll
    for (int mm = L4; mm < GL; mm <<= 1) {
        a.x += __shfl_xor(a.x, mm, 64); a.y += __shfl_xor(a.y, mm, 64);
        a.z += __shfl_xor(a.z, mm, 64); a.w += __shfl_xor(a.w, mm, 64);
    }

    if (g < L4) {
        const ushort4 t = *(const ushort4*)((const char*)y + (size_t)node * (F * 2) + ub);
        const float d = dinv[node];
        float4 r;
        r.x = fmaxf(d * (a.x + bf2f(t.x)) + gload(b, 4 * u + 0, isbf), 0.f);
        r.y = fmaxf(d * (a.y + bf2f(t.y)) + gload(b, 4 * u + 1, isbf), 0.f);
        r.z = fmaxf(d * (a.z + bf2f(t.z)) + gload(b, 4 * u + 2, isbf), 0.f);
        r.w = fmaxf(d * (a.w + bf2f(t.w)) + gload(b, 4 * u + 3, isbf), 0.f);
        ushort4 w;
        w.x = f2bfu(r.x); w.y = f2bfu(r.y); w.z = f2bfu(r.z); w.w = f2bfu(r.w);
        *(ushort4*)(out + (size_t)node * F + 4 * u) = w;
    }
}

// ---------- layer-3 aggregate fused with dense head ----------
__global__ void __launch_bounds__(256) aggregate3_head(const unsigned short* __restrict__ y,
                                                       const int* __restrict__ csr,
                                                       const int* __restrict__ rowptr,
                                                       const int* __restrict__ cnt,
                                                       const float* __restrict__ dinv,
                                                       const void* __restrict__ b3,
                                                       const unsigned short* __restrict__ f1,
                                                       const unsigned short* __restrict__ f2,
                                                       const void* __restrict__ Wfc,
                                                       const void* __restrict__ bfc,
                                                       void* __restrict__ out,
                                                       int n, const int* __restrict__ flag) {
    const int isbf = *flag;
    __shared__ float Ws[112 * 16];
    for (int i = threadIdx.x; i < 112 * 16; i += 256) Ws[i] = gload(Wfc, i, isbf);
    __syncthreads();                              // before ANY return

    const int lane = threadIdx.x & 63;
    const int wv   = (blockIdx.x * 256 + threadIdx.x) >> 6;
    const int node = wv * 4 + (lane >> 4);        // F=16: GL=16, NPW=4
    if (node >= n) return;
    const int g  = lane & 15;
    const int e  = g >> 2;
    const int u  = g & 3;
    const int ub = u * 8;

    float4 a = make_float4(0.f, 0.f, 0.f, 0.f);
    agg_core<16, 2>(y, csr, rowptr[node], cnt[node], e, ub, a);

#pragma unroll
    for (int mm = 4; mm < 16; mm <<= 1) {
        a.x += __shfl_xor(a.x, mm, 64); a.y += __shfl_xor(a.y, mm, 64);
        a.z += __shfl_xor(a.z, mm, 64); a.w += __shfl_xor(a.w, mm, 64);
    }

    // epilogue in ALL lanes (every lane holds the quad for u = g&3)
    float4 r;
    {
        const ushort4 t = *(const ushort4*)((const char*)y + (size_t)node * 32 + ub);
        const float d = dinv[node];
        r.x = fmaxf(d * (a.x + bf2f(t.x)) + gload(b3, 4 * u + 0, isbf), 0.f);
        r.y = fmaxf(d * (a.y + bf2f(t.y)) + gload(b3, 4 * u + 1, isbf), 0.f);
        r.z = fmaxf(d * (a.z + bf2f(t.z)) + gload(b3, 4 * u + 2, isbf), 0.f);
        r.w = fmaxf(d * (a.w + bf2f(t.w)) + gload(b3, 4 * u + 3, isbf), 0.f);
    }

    // ---- head: lane computes output feature f = g for its group's node ----
    const int f = g;
    float acc = gload(bfc, f, isbf);
    const unsigned short* x1 = f1 + (size_t)node * 64;
#pragma unroll
    for (int k4 = 0; k4 < 16; ++k4) {
        const ushort4 xu = *(const ushort4*)(x1 + 4 * k4);
        acc = fmaf(bf2f(xu.x), Ws[(4 * k4 + 0) * 16 + f], acc);
        acc = fmaf(bf2f(xu.y), Ws[(4 * k4 + 1) * 16 + f], acc);
        acc = fmaf(bf2f(xu.z), Ws[(4 * k4 + 2) * 16 + f], acc);
        acc = fmaf(bf2f(xu.w), Ws[(4 * k4 + 3) * 16 + f], acc);
    }
    const unsigned short* x2 = f2 + (size_t)node * 32;
#pragma unroll
    for (int k4 = 0; k4 < 8; ++k4) {
        const ushort4 xu = *(const ushort4*)(x2 + 4 * k4);
        acc = fmaf(bf2f(xu.x), Ws[(64 + 4 * k4 + 0) * 16 + f], acc);
        acc = fmaf(bf2f(xu.y), Ws[(64 + 4 * k4 + 1) * 16 + f], acc);
        acc = fmaf(bf2f(xu.z), Ws[(64 + 4 * k4 + 2) * 16 + f], acc);
        acc = fmaf(bf2f(xu.w), Ws[(64 + 4 * k4 + 3) * 16 + f], acc);
    }
    // f3 via intra-group shuffles: src lane (lane&~15)+(k3>>2) holds comp k3&3
    const int gbase = lane & ~15;
#pragma unroll
    for (int k3 = 0; k3 < 16; k3 += 4) {
        const int src = gbase + (k3 >> 2);
        acc = fmaf(__shfl(r.x, src, 64), Ws[(96 + k3 + 0) * 16 + f], acc);
        acc = fmaf(__shfl(r.y, src, 64), Ws[(96 + k3 + 1) * 16 + f], acc);
        acc = fmaf(__shfl(r.z, src, 64), Ws[(96 + k3 + 2) * 16 + f], acc);
        acc = fmaf(__shfl(r.w, src, 64), Ws[(96 + k3 + 3) * 16 + f], acc);
    }
    acc = fmaxf(acc, 0.f);
    if (isbf) ((unsigned short*)out)[(size_t)node * 16 + f] = f2bfu(acc);
    else      ((float*)out)[(size_t)node * 16 + f] = acc;
}

// ---------- launch ----------
extern "C" void kernel_launch(void* const* d_in, const int* in_sizes, int n_in,
                              void* d_out, int out_size, void* d_ws, size_t ws_size,
                              hipStream_t stream) {
    const int*  edges = (const int*)d_in[0];
    const void* feat  = d_in[1];
    const void* W1    = d_in[2];
    const void* b1    = d_in[3];
    const void* W2    = d_in[4];
    const void* b2    = d_in[5];
    const void* W3    = d_in[6];
    const void* b3    = d_in[7];
    const void* Wfc   = d_in[8];
    const void* bfc   = d_in[9];

    const int E = in_sizes[0] / 2;
    const int N = in_sizes[1] / 128;
    const int* row = edges;
    const int* col = edges + E;

    const int B  = DIVUP(E, CHUNK);    // phase-A blocks (8192-edge chunks, 16 waves each)
    const int NB = DIVUP(N, 256);      // col buckets / phase-B blocks
    const int NBB = NB * B;            // scan length (153K at E=3.2M)

    char* p = (char*)d_ws;
    int*   flag   = (int*)p;               p += 16;
    float* dinv   = (float*)p;             p += (size_t)N * 4;
    int*   cnt    = (int*)p;               p += (size_t)N * 4;
    int*   rowptr = (int*)p;               p += (size_t)N * 4;
    int*   csr    = (int*)p;               p += (size_t)E * 4;
    int*   part   = (int*)p;               p += (size_t)E * 4;   // packed 4B entries
    unsigned short* y  = (unsigned short*)p; p += (size_t)N * 64 * 2;  // gemm output (max 64 feat)
    unsigned short* f1 = (unsigned short*)p; p += (size_t)N * 64 * 2;
    unsigned short* f2 = (unsigned short*)p; p += (size_t)N * 32 * 2;
    int*   cntRB  = (int*)p;               p += (size_t)NBB * 4;
    int*   segoff = (int*)p;               p += (size_t)NBB * 4;
    int*   bsum   = (int*)p;

    // CSR build (also produces cnt, rowptr, dinv) — no global atomics
    parta_hist<<<B, 1024, 0, stream>>>(col, cntRB, E, B, NB);
    const int nb = DIVUP(NBB, 1024);
    scan_block_sums<<<nb, 256, 0, stream>>>(cntRB, bsum, NBB);
    scan_bsum<<<1, 256, 0, stream>>>(bsum, nb, feat, flag);
    scan_final<<<nb, 256, 0, stream>>>(cntRB, bsum, segoff, NBB);
    parta_scatter<<<B, 1024, 0, stream>>>(row, col, segoff, part, E, B, NB);
    csr_build<<<NB, 1024, 0, stream>>>(part, segoff, rowptr, cnt, dinv, csr, E, B, NB, N);

    // layer 1: 128 -> 64, single full-width pass (rows = 128B = full line, SH=0)
    gemm_mfma<128, 64, 0><<<DIVUP(N, 64), 256, 0, stream>>>(feat, W1, dinv, y, N, flag);
    aggregate<64, 0><<<DIVUP(N, 4), 256, 0, stream>>>(y, csr, rowptr, cnt, dinv, b1, f1, N, flag);

    // layer 2: 64 -> 32  (2 nodes/wave)
    gemm_mfma<64, 32, 1><<<DIVUP(N, 64), 256, 0, stream>>>(f1, W2, dinv, y, N, flag);
    aggregate<32, 1><<<DIVUP(N, 8), 256, 0, stream>>>(y, csr, rowptr, cnt, dinv, b2, f2, N, flag);

    // layer 3: 32 -> 16, aggregate + dense head fused (4 nodes/wave)
    gemm_mfma<32, 16, 1><<<DIVUP(N, 64), 256, 0, stream>>>(f2, W3, dinv, y, N, flag);
    aggregate3_head<<<DIVUP(N, 16), 256, 0, stream>>>(y, csr, rowptr, cnt, dinv, b3,
                                                      f1, f2, Wfc, bfc, d_out, N, flag);
}